// Round 3
// baseline (955.420 us; speedup 1.0000x reference)
//
#include <hip/hip_runtime.h>

#define BATCH 16
#define QT    2048
#define KTOT  2048
#define DIM   1024
#define NITEMS (BATCH * (QT / 32))   // 1024 work items (b, 32-row q-block)

typedef __attribute__((ext_vector_type(8))) _Float16 f16x8;
typedef __attribute__((ext_vector_type(4))) _Float16 f16x4;
typedef __attribute__((ext_vector_type(2))) _Float16 f16x2;
typedef __attribute__((ext_vector_type(4))) float    f32x4;
typedef __attribute__((ext_vector_type(2))) float    f32x2;

// ---------------------------------------------------------------------------
// K fp32 -> fp16 (single, no split: fp16 mantissa makes 2-term QK sufficient)
__global__ __launch_bounds__(256) void conv_k(const float* __restrict__ K,
                                              _Float16* __restrict__ Kf) {
    const size_t idx = ((size_t)blockIdx.x * 256 + threadIdx.x) * 8;
    f32x4 a0 = *(const f32x4*)(K + idx);
    f32x4 a1 = *(const f32x4*)(K + idx + 4);
    f16x8 h;
#pragma unroll
    for (int j = 0; j < 4; ++j) { h[j] = (_Float16)a0[j]; h[4 + j] = (_Float16)a1[j]; }
    *(f16x8*)(Kf + idx) = h;
}

// ---------------------------------------------------------------------------
// V[b][kt][d] fp32 -> Vt[b][d][kt] fp16 (PV B-frags become 16B-contiguous)
__global__ __launch_bounds__(256) void trans_v(const float* __restrict__ V,
                                               _Float16* __restrict__ Vt) {
    const int blk = blockIdx.x;
    const int b   = blk >> 9;
    const int kt0 = ((blk >> 4) & 31) << 6;
    const int d0  = (blk & 15) << 6;
    __shared__ _Float16 tbuf[64][65];
    const int tid = threadIdx.x;
    const int cr  = tid >> 4;
    const int c4  = (tid & 15) << 2;
#pragma unroll
    for (int p = 0; p < 4; ++p) {
        const int r = cr + p * 16;
        f32x4 v = *(const f32x4*)(V + ((size_t)(b * KTOT + kt0 + r)) * DIM + d0 + c4);
#pragma unroll
        for (int j = 0; j < 4; ++j) tbuf[r][c4 + j] = (_Float16)v[j];
    }
    __syncthreads();
#pragma unroll
    for (int p = 0; p < 4; ++p) {
        const int dr = cr + p * 16;
        f16x4 o;
#pragma unroll
        for (int j = 0; j < 4; ++j) o[j] = tbuf[c4 + j][dr];
        *(f16x4*)(Vt + ((size_t)(b * DIM + d0 + dr)) * KTOT + kt0 + c4) = o;
    }
}

// ---------------------------------------------------------------------------
// Rows q >= Q_len: reference softmax is exactly uniform over ALL KTOT keys ->
// output = column mean of V. 4 threads per (b,d) row (4x wave count vs r1:
// the old 1-thread/row version had 1 wave/CU -> pure latency-bound).
__global__ __launch_bounds__(256) void fill_mean_vt(const _Float16* __restrict__ Vt,
                                                    const int* __restrict__ Qlen,
                                                    float* __restrict__ out) {
    const int gid  = blockIdx.x * 256 + threadIdx.x;  // 0 .. 65535
    const int row  = gid >> 2;                        // (b,d) row 0..16383
    const int part = gid & 3;
    const int b = row >> 10, d = row & 1023;
    const f16x8* src = (const f16x8*)(Vt + (size_t)row * KTOT) + part * (KTOT / 32);
    float s = 0.0f;
    for (int i = 0; i < KTOT / 32; ++i) {             // 64 x f16x8 per part
        f16x8 v = src[i];
#pragma unroll
        for (int j = 0; j < 8; ++j) s += (float)v[j];
    }
    s += __shfl_xor(s, 1, 64);
    s += __shfl_xor(s, 2, 64);                        // quad-reduce: full row sum
    const float mv = s * (1.0f / (float)KTOT);
    const int qlen = Qlen[b];
    for (int q = qlen + part; q < QT; q += 4)
        out[((size_t)(b * QT + q)) * DIM + d] = mv;
}

// ---------------------------------------------------------------------------
// Main flash kernel. 512 thr = 8 waves; wave w owns D-slice [128w,128w+128).
// 32 q-rows per item; persistent blocks pull items from an atomic queue.
// QK^T = Qhi*K + Qlo*K (fp16 split Q, plain fp16 K).
//
// Pipeline (one barrier per tile), K prefetch now 2 tiles deep (kfA/kfB with
// compile-time names -- runtime-indexed reg arrays would go to scratch):
//   body T:  QK(T)->sred[T&1] | softmax(T-1) | K-load(T+2)->same buf as QK(T)
//            BARRIER
//            PV(T-1) reads pbuf/arow[(T-1)&1] + vf  |  V-load(T) -> vf
__global__ __launch_bounds__(512, 2) void attn_main(
    const float* __restrict__ Q, const int* __restrict__ Qlen, const int* __restrict__ Klen,
    const _Float16* __restrict__ Kf, const _Float16* __restrict__ Vt,
    float* __restrict__ out, unsigned* __restrict__ counter) {

    __shared__ float    sred[2][8][32][34];   // pad 34: f32x2 reads stay 8B-aligned, banks 2-way
    __shared__ _Float16 pbuf[2][32][40];      // row stride 80B -> 16B-aligned frag reads
    __shared__ float    arow[2][32];
    __shared__ float    lrow[32];
    __shared__ unsigned item_s;

    const int tid  = threadIdx.x;
    const int w    = tid >> 6;            // wave 0..7
    const int ln   = tid & 63;
    const int l16  = ln & 15;
    const int quad = ln >> 4;
    const int d0   = w << 7;              // this wave's D-slice base
    // softmax mapping: row sr (0..31) owned by 16 consecutive tids (same wave)
    const int sr  = tid >> 4;
    const int scg = tid & 15;

    for (;;) {
        __syncthreads();                  // protect item_s + LDS reuse across items
        if (tid == 0) item_s = atomicAdd(counter, 1u);
        __syncthreads();
        const unsigned item = item_s;
        if (item >= NITEMS) break;
        const int b    = item >> 6;
        const int qt   = (item & 63) << 5;
        const int qlen = Qlen[b];
        if (qt >= qlen) continue;         // fill_mean_vt covers these rows
        const int klen = Klen[b];
        const int nkt  = (klen + 31) >> 5;

        // --- Q fragments (A-layout), fp16 hi/lo split, resident ------------
        f16x8 qh[2][4], ql[2][4];
#pragma unroll
        for (int mi = 0; mi < 2; ++mi)
#pragma unroll
            for (int kc = 0; kc < 4; ++kc) {
                const float* src = Q + ((size_t)(b * QT + qt + mi * 16 + l16)) * DIM
                                     + d0 + kc * 32 + quad * 8;
                f32x4 a0 = *(const f32x4*)src;
                f32x4 a1 = *(const f32x4*)(src + 4);
                f16x8 h, l;
#pragma unroll
                for (int j = 0; j < 4; ++j) {
                    _Float16 h0 = (_Float16)a0[j];
                    h[j] = h0; l[j] = (_Float16)(a0[j] - (float)h0);
                    _Float16 h1 = (_Float16)a1[j];
                    h[4 + j] = h1; l[4 + j] = (_Float16)(a1[j] - (float)h1);
                }
                qh[mi][kc] = h; ql[mi][kc] = l;
            }

        f32x4 o[2][8];
        const f32x4 fzero = {0.0f, 0.0f, 0.0f, 0.0f};
#pragma unroll
        for (int mi = 0; mi < 2; ++mi)
#pragma unroll
            for (int nd = 0; nd < 8; ++nd) o[mi][nd] = fzero;

        float msx = -3.0e38f, lsx = 0.0f;   // per-row softmax state

        f16x8 kfA[2][4], kfB[2][4];        // 2-deep K prefetch, static names
        f16x8 vf[8];                       // V regs for tile in flight

#define KLOAD(DST, TT)                                                          \
        {                                                                       \
            const _Float16* kb_ = Kf + ((size_t)(b * KTOT + ((TT) << 5) + l16)) * DIM \
                                     + d0 + quad * 8;                           \
            _Pragma("unroll")                                                   \
            for (int ni = 0; ni < 2; ++ni)                                      \
                _Pragma("unroll")                                               \
                for (int kc = 0; kc < 4; ++kc)                                  \
                    DST[ni][kc] = *(const f16x8*)(kb_ + (size_t)(ni * 16) * DIM + kc * 32); \
        }

        KLOAD(kfA, 0);
        if (nkt > 1) KLOAD(kfB, 1);

#define TILE_BODY(T, KFU)                                                       \
        {                                                                       \
            const int t_ = (T);                                                 \
            const int cur_ = t_ & 1, prv_ = cur_ ^ 1;                           \
            if (t_ < nkt) {                                                     \
                f32x4 s00 = fzero, s01 = fzero, s10 = fzero, s11 = fzero;       \
                _Pragma("unroll")                                               \
                for (int kc = 0; kc < 4; ++kc) {                                \
                    s00 = __builtin_amdgcn_mfma_f32_16x16x32_f16(qh[0][kc], KFU[0][kc], s00, 0, 0, 0); \
                    s10 = __builtin_amdgcn_mfma_f32_16x16x32_f16(qh[1][kc], KFU[0][kc], s10, 0, 0, 0); \
                    s00 = __builtin_amdgcn_mfma_f32_16x16x32_f16(ql[0][kc], KFU[0][kc], s00, 0, 0, 0); \
                    s10 = __builtin_amdgcn_mfma_f32_16x16x32_f16(ql[1][kc], KFU[0][kc], s10, 0, 0, 0); \
                    s01 = __builtin_amdgcn_mfma_f32_16x16x32_f16(qh[0][kc], KFU[1][kc], s01, 0, 0, 0); \
                    s11 = __builtin_amdgcn_mfma_f32_16x16x32_f16(qh[1][kc], KFU[1][kc], s11, 0, 0, 0); \
                    s01 = __builtin_amdgcn_mfma_f32_16x16x32_f16(ql[0][kc], KFU[1][kc], s01, 0, 0, 0); \
                    s11 = __builtin_amdgcn_mfma_f32_16x16x32_f16(ql[1][kc], KFU[1][kc], s11, 0, 0, 0); \
                }                                                               \
                _Pragma("unroll")                                               \
                for (int r2 = 0; r2 < 4; ++r2) {                                \
                    sred[cur_][w][quad * 4 + r2][l16]           = s00[r2];      \
                    sred[cur_][w][quad * 4 + r2][16 + l16]      = s01[r2];      \
                    sred[cur_][w][16 + quad * 4 + r2][l16]      = s10[r2];      \
                    sred[cur_][w][16 + quad * 4 + r2][16 + l16] = s11[r2];      \
                }                                                               \
            }                                                                   \
            if (t_ > 0) {                                                       \
                const int kt0p = (t_ - 1) << 5;                                 \
                const int c0 = scg * 2, c1 = c0 + 1;                            \
                float x0 = 0.0f, x1 = 0.0f;                                     \
                _Pragma("unroll")                                               \
                for (int ww = 0; ww < 8; ++ww) {                                \
                    f32x2 xp = *(const f32x2*)&sred[prv_][ww][sr][c0];          \
                    x0 += xp[0]; x1 += xp[1];                                   \
                }                                                               \
                if (kt0p + c0 >= klen) x0 = -3.0e38f;                           \
                if (kt0p + c1 >= klen) x1 = -3.0e38f;                           \
                float pm = fmaxf(x0, x1);                                       \
                _Pragma("unroll")                                               \
                for (int off = 1; off < 16; off <<= 1) pm = fmaxf(pm, __shfl_xor(pm, off, 64)); \
                const float mn    = fmaxf(msx, pm);                             \
                const float alpha = __expf(msx - mn);                           \
                const float p0 = __expf(x0 - mn), p1 = __expf(x1 - mn);         \
                float ps = p0 + p1;                                             \
                _Pragma("unroll")                                               \
                for (int off = 1; off < 16; off <<= 1) ps += __shfl_xor(ps, off, 64); \
                lsx = lsx * alpha + ps;                                         \
                msx = mn;                                                       \
                f16x2 pw; pw[0] = (_Float16)p0; pw[1] = (_Float16)p1;           \
                *(f16x2*)&pbuf[prv_][sr][c0] = pw;                              \
                if (scg == 0) arow[prv_][sr] = alpha;                           \
            }                                                                   \
            if (t_ + 2 < nkt) KLOAD(KFU, t_ + 2);                               \
            __syncthreads();                                                    \
            if (t_ > 0) {                                                       \
                f32x4 av0 = *(const f32x4*)&arow[prv_][quad * 4];               \
                f32x4 av1 = *(const f32x4*)&arow[prv_][16 + quad * 4];          \
                _Pragma("unroll")                                               \
                for (int nd = 0; nd < 8; ++nd) { o[0][nd] *= av0; o[1][nd] *= av1; } \
                f16x8 pa0 = *(const f16x8*)&pbuf[prv_][l16][quad * 8];          \
                f16x8 pa1 = *(const f16x8*)&pbuf[prv_][16 + l16][quad * 8];     \
                _Pragma("unroll")                                               \
                for (int nd = 0; nd < 8; ++nd) {                                \
                    o[0][nd] = __builtin_amdgcn_mfma_f32_16x16x32_f16(pa0, vf[nd], o[0][nd], 0, 0, 0); \
                    o[1][nd] = __builtin_amdgcn_mfma_f32_16x16x32_f16(pa1, vf[nd], o[1][nd], 0, 0, 0); \
                }                                                               \
            }                                                                   \
            if (t_ < nkt) {                                                     \
                const int kt0v = t_ << 5;                                       \
                _Pragma("unroll")                                               \
                for (int nd = 0; nd < 8; ++nd)                                  \
                    vf[nd] = *(const f16x8*)(Vt + ((size_t)(b * DIM + d0 + nd * 16 + l16)) * KTOT \
                                             + kt0v + quad * 8);                \
            }                                                                   \
        }

        for (int t = 0; t <= nkt; t += 2) {
            TILE_BODY(t, kfA);
            if (t + 1 <= nkt) TILE_BODY(t + 1, kfB);
        }
#undef TILE_BODY
#undef KLOAD

        // --- epilogue -------------------------------------------------------
        if (scg == 0) lrow[sr] = lsx;
        __syncthreads();
        f32x4 li0, li1;
#pragma unroll
        for (int r2 = 0; r2 < 4; ++r2) {
            li0[r2] = 1.0f / lrow[quad * 4 + r2];
            li1[r2] = 1.0f / lrow[16 + quad * 4 + r2];
        }
#pragma unroll
        for (int mi = 0; mi < 2; ++mi)
#pragma unroll
            for (int r2 = 0; r2 < 4; ++r2) {
                const int row = qt + mi * 16 + quad * 4 + r2;
                if (row < qlen) {
                    const float inv = mi ? li1[r2] : li0[r2];
#pragma unroll
                    for (int nd = 0; nd < 8; ++nd)
                        out[((size_t)(b * QT + row)) * DIM + d0 + nd * 16 + l16] =
                            o[mi][nd][r2] * inv;
                }
            }
    }
}

// ---------------------------------------------------------------------------
// Fallback path (only if ws too small — round-1 evidence says it isn't)
__global__ __launch_bounds__(256) void fill_mean_f32(const float* __restrict__ V,
                                                     const int* __restrict__ Qlen,
                                                     float* __restrict__ out) {
    const int b  = blockIdx.x >> 4;
    const int d0 = (blockIdx.x & 15) << 6;
    const int qlen = Qlen[b];
    const int tid = threadIdx.x;
    const int dc = d0 + (tid & 63);
    const int part = tid >> 6;
    __shared__ float red[4][64];
    __shared__ float mcol[64];
    float sm = 0.0f;
    for (int kt = part; kt < KTOT; kt += 4)
        sm += V[((size_t)(b * KTOT + kt)) * DIM + dc];
    red[part][tid & 63] = sm;
    __syncthreads();
    if (tid < 64)
        mcol[tid] = (red[0][tid] + red[1][tid] + red[2][tid] + red[3][tid]) * (1.0f / (float)KTOT);
    __syncthreads();
    const float mv = mcol[tid & 63];
    for (int q = qlen + part; q < QT; q += 4)
        out[((size_t)(b * QT + q)) * DIM + dc] = mv;
}

__global__ __launch_bounds__(512) void attn_naive(
    const float* __restrict__ Q, const float* __restrict__ K, const float* __restrict__ V,
    const int* __restrict__ Qlen, const int* __restrict__ Klen, float* __restrict__ out) {
    const int blk  = blockIdx.x;
    const int b    = blk >> 8;
    const int qb   = (blk & 255) << 3;
    const int qlen = Qlen[b];
    if (qb >= qlen) return;
    const int klen = Klen[b];
    const int tid  = threadIdx.x;
    const int wid  = tid >> 6, ln = tid & 63;
    const int q    = qb + wid;
    __shared__ float kbuf[1024], vbuf[1024];
    f32x4 qr[4];
#pragma unroll
    for (int i = 0; i < 4; ++i)
        qr[i] = *(const f32x4*)(Q + ((size_t)(b * QT + q)) * DIM + i * 256 + ln * 4);
    const f32x4 fzero = {0.0f, 0.0f, 0.0f, 0.0f};
    f32x4 acc[4] = {fzero, fzero, fzero, fzero};
    float m = -3.0e38f, l = 0.0f;
    for (int kt = 0; kt < klen; ++kt) {
        __syncthreads();
        if (tid < 256)
            *(f32x4*)&kbuf[tid * 4] = *(const f32x4*)(K + ((size_t)(b * KTOT + kt)) * DIM + tid * 4);
        else
            *(f32x4*)&vbuf[(tid - 256) * 4] =
                *(const f32x4*)(V + ((size_t)(b * KTOT + kt)) * DIM + (tid - 256) * 4);
        __syncthreads();
        float sp = 0.0f;
#pragma unroll
        for (int i = 0; i < 4; ++i) {
            f32x4 kv = *(const f32x4*)&kbuf[i * 256 + ln * 4];
            sp += qr[i][0] * kv[0] + qr[i][1] * kv[1] + qr[i][2] * kv[2] + qr[i][3] * kv[3];
        }
#pragma unroll
        for (int off = 1; off < 64; off <<= 1) sp += __shfl_xor(sp, off, 64);
        const float mn = fmaxf(m, sp);
        const float a  = __expf(m - mn);
        const float p  = __expf(sp - mn);
        l = l * a + p; m = mn;
#pragma unroll
        for (int i = 0; i < 4; ++i) {
            f32x4 vv = *(const f32x4*)&vbuf[i * 256 + ln * 4];
            acc[i] = acc[i] * a + vv * p;
        }
    }
    if (q < qlen) {
        const float inv = 1.0f / l;
#pragma unroll
        for (int i = 0; i < 4; ++i)
            *(f32x4*)(out + ((size_t)(b * QT + q)) * DIM + i * 256 + ln * 4) = acc[i] * inv;
    }
}

// ---------------------------------------------------------------------------
extern "C" void kernel_launch(void* const* d_in, const int* in_sizes, int n_in,
                              void* d_out, int out_size, void* d_ws, size_t ws_size,
                              hipStream_t stream) {
    (void)in_sizes; (void)n_in; (void)out_size;
    const float* Q    = (const float*)d_in[0];
    const float* K    = (const float*)d_in[1];
    const float* V    = (const float*)d_in[2];
    const int*   Qlen = (const int*)d_in[3];
    const int*   Klen = (const int*)d_in[4];
    float*       out  = (float*)d_out;

    const size_t HALF = (size_t)BATCH * KTOT * DIM;          // 33,554,432 elements
    const size_t NEED = HALF * 2 /*Kf*/ * sizeof(_Float16) + 64; // ~128 MB + counter
    if (ws_size >= NEED) {
        _Float16* kf = (_Float16*)d_ws;
        _Float16* vt = kf + HALF;
        unsigned* ctr = (unsigned*)((char*)d_ws + HALF * 2 * sizeof(_Float16));
        hipMemsetAsync(ctr, 0, sizeof(unsigned), stream);
        conv_k<<<dim3(16384), dim3(256), 0, stream>>>(K, kf);
        trans_v<<<dim3(8192), dim3(256), 0, stream>>>(V, vt);
        fill_mean_vt<<<dim3(256), dim3(256), 0, stream>>>(vt, Qlen, out);
        attn_main<<<dim3(256), dim3(512), 0, stream>>>(Q, Qlen, Klen, kf, vt, out, ctr);
    } else {
        fill_mean_f32<<<dim3(BATCH * 16), dim3(256), 0, stream>>>(V, Qlen, out);
        attn_naive<<<dim3(4096), dim3(512), 0, stream>>>(Q, K, V, Qlen, Klen, out);
    }
}

// Round 4
// 740.643 us; speedup vs baseline: 1.2900x; 1.2900x over previous
//
#include <hip/hip_runtime.h>

#define BATCH 16
#define QT    2048
#define KTOT  2048
#define DIM   1024
#define NITEMS (BATCH * (QT / 32))   // 1024 work items (b, 32-row q-block)

typedef __attribute__((ext_vector_type(8))) _Float16 f16x8;
typedef __attribute__((ext_vector_type(4))) _Float16 f16x4;
typedef __attribute__((ext_vector_type(2))) _Float16 f16x2;
typedef __attribute__((ext_vector_type(4))) float    f32x4;
typedef __attribute__((ext_vector_type(2))) float    f32x2;

// ---------------------------------------------------------------------------
// K fp32 -> fp16 (single, no split: fp16 mantissa makes 2-term QK sufficient)
__global__ __launch_bounds__(256) void conv_k(const float* __restrict__ K,
                                              _Float16* __restrict__ Kf) {
    const size_t idx = ((size_t)blockIdx.x * 256 + threadIdx.x) * 8;
    f32x4 a0 = *(const f32x4*)(K + idx);
    f32x4 a1 = *(const f32x4*)(K + idx + 4);
    f16x8 h;
#pragma unroll
    for (int j = 0; j < 4; ++j) { h[j] = (_Float16)a0[j]; h[4 + j] = (_Float16)a1[j]; }
    *(f16x8*)(Kf + idx) = h;
}

// ---------------------------------------------------------------------------
// V[b][kt][d] fp32 -> Vt[b][d][kt] fp16 (PV B-frags become 16B-contiguous)
__global__ __launch_bounds__(256) void trans_v(const float* __restrict__ V,
                                               _Float16* __restrict__ Vt) {
    const int blk = blockIdx.x;
    const int b   = blk >> 9;
    const int kt0 = ((blk >> 4) & 31) << 6;
    const int d0  = (blk & 15) << 6;
    __shared__ _Float16 tbuf[64][65];
    const int tid = threadIdx.x;
    const int cr  = tid >> 4;
    const int c4  = (tid & 15) << 2;
#pragma unroll
    for (int p = 0; p < 4; ++p) {
        const int r = cr + p * 16;
        f32x4 v = *(const f32x4*)(V + ((size_t)(b * KTOT + kt0 + r)) * DIM + d0 + c4);
#pragma unroll
        for (int j = 0; j < 4; ++j) tbuf[r][c4 + j] = (_Float16)v[j];
    }
    __syncthreads();
#pragma unroll
    for (int p = 0; p < 4; ++p) {
        const int dr = cr + p * 16;
        f16x4 o;
#pragma unroll
        for (int j = 0; j < 4; ++j) o[j] = tbuf[c4 + j][dr];
        *(f16x4*)(Vt + ((size_t)(b * DIM + d0 + dr)) * KTOT + kt0 + c4) = o;
    }
}

// ---------------------------------------------------------------------------
// Rows q >= Q_len: reference softmax is exactly uniform over ALL KTOT keys ->
// output = column mean of V. 4 threads per (b,d) row.
__global__ __launch_bounds__(256) void fill_mean_vt(const _Float16* __restrict__ Vt,
                                                    const int* __restrict__ Qlen,
                                                    float* __restrict__ out) {
    const int gid  = blockIdx.x * 256 + threadIdx.x;  // 0 .. 65535
    const int row  = gid >> 2;                        // (b,d) row 0..16383
    const int part = gid & 3;
    const int b = row >> 10, d = row & 1023;
    const f16x8* src = (const f16x8*)(Vt + (size_t)row * KTOT) + part * (KTOT / 32);
    float s = 0.0f;
    for (int i = 0; i < KTOT / 32; ++i) {             // 64 x f16x8 per part
        f16x8 v = src[i];
#pragma unroll
        for (int j = 0; j < 8; ++j) s += (float)v[j];
    }
    s += __shfl_xor(s, 1, 64);
    s += __shfl_xor(s, 2, 64);                        // quad-reduce: full row sum
    const float mv = s * (1.0f / (float)KTOT);
    const int qlen = Qlen[b];
    for (int q = qlen + part; q < QT; q += 4)
        out[((size_t)(b * QT + q)) * DIM + d] = mv;
}

// ---------------------------------------------------------------------------
// Main flash kernel. 512 thr = 8 waves; wave w owns D-slice [128w,128w+128).
// 32 q-rows per item; persistent blocks pull items from PER-XCD queues:
// group x (= blockIdx & 7, HW round-robin -> same XCD) owns batches {2x,2x+1},
// so each XCD's 32 blocks stream the same 16 MB Kf/Vt working set through
// their local L2 in loose lockstep (re-reads become L2 hits, not LLC).
// Queue-stealing across groups bounds load imbalance.
//
// Pipeline (R1-proven, ONE barrier per tile, single-buffered K prefetch):
//   iter t:  QK(t)->sred[t&1] | softmax(t-1) | K-load(t+1)
//            BARRIER
//            PV(t-1) reads pbuf/arow[(t-1)&1] + vf  |  V-load(t) -> vf
__global__ __launch_bounds__(512, 2) void attn_main(
    const float* __restrict__ Q, const int* __restrict__ Qlen, const int* __restrict__ Klen,
    const _Float16* __restrict__ Kf, const _Float16* __restrict__ Vt,
    float* __restrict__ out, unsigned* __restrict__ counter) {

    __shared__ float    sred[2][8][32][34];   // pad 34: f32x2 reads 8B-aligned, 2-way banks (free)
    __shared__ _Float16 pbuf[2][32][40];      // row stride 80B -> 16B-aligned frag reads
    __shared__ float    arow[2][32];
    __shared__ float    lrow[32];
    __shared__ unsigned item_s;

    const int tid  = threadIdx.x;
    const int w    = tid >> 6;            // wave 0..7
    const int ln   = tid & 63;
    const int l16  = ln & 15;
    const int quad = ln >> 4;
    const int d0   = w << 7;              // this wave's D-slice base
    // softmax mapping: row sr (0..31) owned by 16 consecutive tids (same wave)
    const int sr  = tid >> 4;
    const int scg = tid & 15;

    // per-XCD queue state (tid 0 only, persists in registers across items)
    const unsigned bxcd = (unsigned)(blockIdx.x & 7);
    unsigned gx = bxcd;
    int goff = 0;

    for (;;) {
        __syncthreads();                  // protect item_s + LDS reuse across items
        if (tid == 0) {
            unsigned pick = 0xFFFFFFFFu;
            while (goff < 8) {
                unsigned it = atomicAdd(&counter[gx], 1u);
                if (it < 128u) { pick = gx * 128u + it; break; }
                ++goff;
                gx = (bxcd + (unsigned)goff) & 7u;
            }
            item_s = pick;
        }
        __syncthreads();
        const unsigned item = item_s;
        if (item == 0xFFFFFFFFu) break;
        const int grp  = (int)(item >> 7);           // group 0..7
        const int ii   = (int)(item & 127u);
        const int b    = (grp << 1) + (ii >> 6);     // group owns batches {2g, 2g+1}
        const int qt   = (ii & 63) << 5;
        const int qlen = Qlen[b];
        if (qt >= qlen) continue;         // fill_mean_vt covers these rows
        const int klen = Klen[b];
        const int nkt  = (klen + 31) >> 5;

        // --- Q fragments (A-layout), fp16 hi/lo split, resident ------------
        f16x8 qh[2][4], ql[2][4];
#pragma unroll
        for (int mi = 0; mi < 2; ++mi)
#pragma unroll
            for (int kc = 0; kc < 4; ++kc) {
                const float* src = Q + ((size_t)(b * QT + qt + mi * 16 + l16)) * DIM
                                     + d0 + kc * 32 + quad * 8;
                f32x4 a0 = *(const f32x4*)src;
                f32x4 a1 = *(const f32x4*)(src + 4);
                f16x8 h, l;
#pragma unroll
                for (int j = 0; j < 4; ++j) {
                    _Float16 h0 = (_Float16)a0[j];
                    h[j] = h0; l[j] = (_Float16)(a0[j] - (float)h0);
                    _Float16 h1 = (_Float16)a1[j];
                    h[4 + j] = h1; l[4 + j] = (_Float16)(a1[j] - (float)h1);
                }
                qh[mi][kc] = h; ql[mi][kc] = l;
            }

        f32x4 o[2][8];
        const f32x4 fzero = {0.0f, 0.0f, 0.0f, 0.0f};
#pragma unroll
        for (int mi = 0; mi < 2; ++mi)
#pragma unroll
            for (int nd = 0; nd < 8; ++nd) o[mi][nd] = fzero;

        float msx = -3.0e38f, lsx = 0.0f;   // per-row softmax state

        // --- K preload for tile 0 (single-buffered: R3's 2-deep spilled) ---
        f16x8 kf[2][4];
        {
            const _Float16* kb = Kf + ((size_t)(b * KTOT + l16)) * DIM + d0 + quad * 8;
#pragma unroll
            for (int ni = 0; ni < 2; ++ni)
#pragma unroll
                for (int kc = 0; kc < 4; ++kc)
                    kf[ni][kc] = *(const f16x8*)(kb + (size_t)(ni * 16) * DIM + kc * 32);
        }

        f16x8 vf[8];                       // V regs for tile in flight

        for (int t = 0; t <= nkt; ++t) {
            const int cur = t & 1, prv = cur ^ 1;

            // --- QK^T(t) over this wave's slice (2-term fp16) --------------
            if (t < nkt) {
                f32x4 s00 = fzero, s01 = fzero, s10 = fzero, s11 = fzero;
#pragma unroll
                for (int kc = 0; kc < 4; ++kc) {
                    s00 = __builtin_amdgcn_mfma_f32_16x16x32_f16(qh[0][kc], kf[0][kc], s00, 0, 0, 0);
                    s10 = __builtin_amdgcn_mfma_f32_16x16x32_f16(qh[1][kc], kf[0][kc], s10, 0, 0, 0);
                    s00 = __builtin_amdgcn_mfma_f32_16x16x32_f16(ql[0][kc], kf[0][kc], s00, 0, 0, 0);
                    s10 = __builtin_amdgcn_mfma_f32_16x16x32_f16(ql[1][kc], kf[0][kc], s10, 0, 0, 0);
                    s01 = __builtin_amdgcn_mfma_f32_16x16x32_f16(qh[0][kc], kf[1][kc], s01, 0, 0, 0);
                    s11 = __builtin_amdgcn_mfma_f32_16x16x32_f16(qh[1][kc], kf[1][kc], s11, 0, 0, 0);
                    s01 = __builtin_amdgcn_mfma_f32_16x16x32_f16(ql[0][kc], kf[1][kc], s01, 0, 0, 0);
                    s11 = __builtin_amdgcn_mfma_f32_16x16x32_f16(ql[1][kc], kf[1][kc], s11, 0, 0, 0);
                }
#pragma unroll
                for (int r2 = 0; r2 < 4; ++r2) {
                    sred[cur][w][quad * 4 + r2][l16]           = s00[r2];
                    sred[cur][w][quad * 4 + r2][16 + l16]      = s01[r2];
                    sred[cur][w][16 + quad * 4 + r2][l16]      = s10[r2];
                    sred[cur][w][16 + quad * 4 + r2][16 + l16] = s11[r2];
                }
            }

            // --- softmax(t-1): thread (sr, scg) owns cols 2scg, 2scg+1 -----
            if (t > 0) {
                const int kt0p = (t - 1) << 5;
                const int c0 = scg * 2, c1 = c0 + 1;
                float x0 = 0.0f, x1 = 0.0f;
#pragma unroll
                for (int ww = 0; ww < 8; ++ww) {
                    f32x2 xp = *(const f32x2*)&sred[prv][ww][sr][c0];
                    x0 += xp[0]; x1 += xp[1];
                }
                if (kt0p + c0 >= klen) x0 = -3.0e38f;
                if (kt0p + c1 >= klen) x1 = -3.0e38f;
                float pm = fmaxf(x0, x1);
#pragma unroll
                for (int off = 1; off < 16; off <<= 1) pm = fmaxf(pm, __shfl_xor(pm, off, 64));
                const float mn    = fmaxf(msx, pm);
                const float alpha = __expf(msx - mn);
                const float p0 = __expf(x0 - mn), p1 = __expf(x1 - mn);
                float ps = p0 + p1;
#pragma unroll
                for (int off = 1; off < 16; off <<= 1) ps += __shfl_xor(ps, off, 64);
                lsx = lsx * alpha + ps;
                msx = mn;
                f16x2 pw; pw[0] = (_Float16)p0; pw[1] = (_Float16)p1;
                *(f16x2*)&pbuf[prv][sr][c0] = pw;
                if (scg == 0) arow[prv][sr] = alpha;
            }

            // --- K prefetch for tile t+1 (issued pre-barrier) --------------
            if (t + 1 < nkt) {
                const int ktn = (t + 1) << 5;
                const _Float16* kb = Kf + ((size_t)(b * KTOT + ktn + l16)) * DIM
                                        + d0 + quad * 8;
#pragma unroll
                for (int ni = 0; ni < 2; ++ni)
#pragma unroll
                    for (int kc = 0; kc < 4; ++kc)
                        kf[ni][kc] = *(const f16x8*)(kb + (size_t)(ni * 16) * DIM + kc * 32);
            }

            __syncthreads();               // the ONE barrier per tile

            // --- PV(t-1): rescale O, then MFMA with vf ---------------------
            if (t > 0) {
                f32x4 av0 = *(const f32x4*)&arow[prv][quad * 4];
                f32x4 av1 = *(const f32x4*)&arow[prv][16 + quad * 4];
#pragma unroll
                for (int nd = 0; nd < 8; ++nd) { o[0][nd] *= av0; o[1][nd] *= av1; }

                f16x8 pa0 = *(const f16x8*)&pbuf[prv][l16][quad * 8];
                f16x8 pa1 = *(const f16x8*)&pbuf[prv][16 + l16][quad * 8];
#pragma unroll
                for (int nd = 0; nd < 8; ++nd) {
                    o[0][nd] = __builtin_amdgcn_mfma_f32_16x16x32_f16(pa0, vf[nd], o[0][nd], 0, 0, 0);
                    o[1][nd] = __builtin_amdgcn_mfma_f32_16x16x32_f16(pa1, vf[nd], o[1][nd], 0, 0, 0);
                }
            }

            // --- V load for tile t (consumed next iter, post-next-barrier) -
            if (t < nkt) {
                const int kt0v = t << 5;
#pragma unroll
                for (int nd = 0; nd < 8; ++nd)
                    vf[nd] = *(const f16x8*)(Vt + ((size_t)(b * DIM + d0 + nd * 16 + l16)) * KTOT
                                             + kt0v + quad * 8);
            }
        }

        // --- epilogue -------------------------------------------------------
        if (scg == 0) lrow[sr] = lsx;
        __syncthreads();
        f32x4 li0, li1;
#pragma unroll
        for (int r2 = 0; r2 < 4; ++r2) {
            li0[r2] = 1.0f / lrow[quad * 4 + r2];
            li1[r2] = 1.0f / lrow[16 + quad * 4 + r2];
        }
#pragma unroll
        for (int mi = 0; mi < 2; ++mi)
#pragma unroll
            for (int r2 = 0; r2 < 4; ++r2) {
                const int row = qt + mi * 16 + quad * 4 + r2;
                if (row < qlen) {
                    const float inv = mi ? li1[r2] : li0[r2];
#pragma unroll
                    for (int nd = 0; nd < 8; ++nd)
                        out[((size_t)(b * QT + row)) * DIM + d0 + nd * 16 + l16] =
                            o[mi][nd][r2] * inv;
                }
            }
    }
}

// ---------------------------------------------------------------------------
// Fallback path (only if ws too small — round-1 evidence says it isn't)
__global__ __launch_bounds__(256) void fill_mean_f32(const float* __restrict__ V,
                                                     const int* __restrict__ Qlen,
                                                     float* __restrict__ out) {
    const int b  = blockIdx.x >> 4;
    const int d0 = (blockIdx.x & 15) << 6;
    const int qlen = Qlen[b];
    const int tid = threadIdx.x;
    const int dc = d0 + (tid & 63);
    const int part = tid >> 6;
    __shared__ float red[4][64];
    __shared__ float mcol[64];
    float sm = 0.0f;
    for (int kt = part; kt < KTOT; kt += 4)
        sm += V[((size_t)(b * KTOT + kt)) * DIM + dc];
    red[part][tid & 63] = sm;
    __syncthreads();
    if (tid < 64)
        mcol[tid] = (red[0][tid] + red[1][tid] + red[2][tid] + red[3][tid]) * (1.0f / (float)KTOT);
    __syncthreads();
    const float mv = mcol[tid & 63];
    for (int q = qlen + part; q < QT; q += 4)
        out[((size_t)(b * QT + q)) * DIM + dc] = mv;
}

__global__ __launch_bounds__(512) void attn_naive(
    const float* __restrict__ Q, const float* __restrict__ K, const float* __restrict__ V,
    const int* __restrict__ Qlen, const int* __restrict__ Klen, float* __restrict__ out) {
    const int blk  = blockIdx.x;
    const int b    = blk >> 8;
    const int qb   = (blk & 255) << 3;
    const int qlen = Qlen[b];
    if (qb >= qlen) return;
    const int klen = Klen[b];
    const int tid  = threadIdx.x;
    const int wid  = tid >> 6, ln = tid & 63;
    const int q    = qb + wid;
    __shared__ float kbuf[1024], vbuf[1024];
    f32x4 qr[4];
#pragma unroll
    for (int i = 0; i < 4; ++i)
        qr[i] = *(const f32x4*)(Q + ((size_t)(b * QT + q)) * DIM + i * 256 + ln * 4);
    const f32x4 fzero = {0.0f, 0.0f, 0.0f, 0.0f};
    f32x4 acc[4] = {fzero, fzero, fzero, fzero};
    float m = -3.0e38f, l = 0.0f;
    for (int kt = 0; kt < klen; ++kt) {
        __syncthreads();
        if (tid < 256)
            *(f32x4*)&kbuf[tid * 4] = *(const f32x4*)(K + ((size_t)(b * KTOT + kt)) * DIM + tid * 4);
        else
            *(f32x4*)&vbuf[(tid - 256) * 4] =
                *(const f32x4*)(V + ((size_t)(b * KTOT + kt)) * DIM + (tid - 256) * 4);
        __syncthreads();
        float sp = 0.0f;
#pragma unroll
        for (int i = 0; i < 4; ++i) {
            f32x4 kv = *(const f32x4*)&kbuf[i * 256 + ln * 4];
            sp += qr[i][0] * kv[0] + qr[i][1] * kv[1] + qr[i][2] * kv[2] + qr[i][3] * kv[3];
        }
#pragma unroll
        for (int off = 1; off < 64; off <<= 1) sp += __shfl_xor(sp, off, 64);
        const float mn = fmaxf(m, sp);
        const float a  = __expf(m - mn);
        const float p  = __expf(sp - mn);
        l = l * a + p; m = mn;
#pragma unroll
        for (int i = 0; i < 4; ++i) {
            f32x4 vv = *(const f32x4*)&vbuf[i * 256 + ln * 4];
            acc[i] = acc[i] * a + vv * p;
        }
    }
    if (q < qlen) {
        const float inv = 1.0f / l;
#pragma unroll
        for (int i = 0; i < 4; ++i)
            *(f32x4*)(out + ((size_t)(b * QT + q)) * DIM + i * 256 + ln * 4) = acc[i] * inv;
    }
}

// ---------------------------------------------------------------------------
extern "C" void kernel_launch(void* const* d_in, const int* in_sizes, int n_in,
                              void* d_out, int out_size, void* d_ws, size_t ws_size,
                              hipStream_t stream) {
    (void)in_sizes; (void)n_in; (void)out_size;
    const float* Q    = (const float*)d_in[0];
    const float* K    = (const float*)d_in[1];
    const float* V    = (const float*)d_in[2];
    const int*   Qlen = (const int*)d_in[3];
    const int*   Klen = (const int*)d_in[4];
    float*       out  = (float*)d_out;

    const size_t HALF = (size_t)BATCH * KTOT * DIM;          // 33,554,432 elements
    const size_t NEED = HALF * 2 /*Kf*/ * sizeof(_Float16) + 64; // ~128 MB + counters
    if (ws_size >= NEED) {
        _Float16* kf = (_Float16*)d_ws;
        _Float16* vt = kf + HALF;
        unsigned* ctr = (unsigned*)((char*)d_ws + HALF * 2 * sizeof(_Float16));
        hipMemsetAsync(ctr, 0, 8 * sizeof(unsigned), stream);   // 8 per-XCD queues
        conv_k<<<dim3(16384), dim3(256), 0, stream>>>(K, kf);
        trans_v<<<dim3(8192), dim3(256), 0, stream>>>(V, vt);
        fill_mean_vt<<<dim3(256), dim3(256), 0, stream>>>(vt, Qlen, out);
        attn_main<<<dim3(256), dim3(512), 0, stream>>>(Q, Qlen, Klen, kf, vt, out, ctr);
    } else {
        fill_mean_f32<<<dim3(BATCH * 16), dim3(256), 0, stream>>>(V, Qlen, out);
        attn_naive<<<dim3(4096), dim3(512), 0, stream>>>(Q, K, V, Qlen, Klen, out);
    }
}